// Round 1
// baseline (11288.823 us; speedup 1.0000x reference)
//
#include <hip/hip_runtime.h>
#include <hip/hip_bf16.h>
#include <math.h>

// Problem constants (B,T,E,H,D) = (4,2048,1024,16,64)
constexpr int Bc  = 4;
constexpr int Tc  = 2048;
constexpr int Ec  = 1024;
constexpr int Hc  = 16;
constexpr int Dc  = 64;
constexpr int HDc = Hc * Dc;   // 1024
constexpr int Kc  = Tc;        // 2048 (mems=None)
constexpr float SCALE = 0.125f; // 1/sqrt(D)

// ---------------------------------------------------------------------------
// pe table: pe[r, 2i] = sin(r*div_i), pe[r, 2i+1] = cos(r*div_i)
// div_i = exp(-i * 2*ln(10000)/E)
// ---------------------------------------------------------------------------
__global__ void pe_kernel(float* __restrict__ pe) {
  int idx = blockIdx.x * blockDim.x + threadIdx.x;
  if (idx >= Kc * (Ec / 2)) return;
  int r = idx / (Ec / 2);
  int i = idx % (Ec / 2);
  float div = __expf((float)i * -0.017988946039015984f); // -2*ln(10000)/1024
  float ang = (float)r * div;
  pe[(size_t)r * Ec + 2 * i]     = sinf(ang);
  pe[(size_t)r * Ec + 2 * i + 1] = cosf(ang);
}

// ---------------------------------------------------------------------------
// Generic fp32 tiled GEMM: C[m,n] = sum_k A[m,k] * B[n,k]   (B given [N,K])
// 64x64 tile, BK=16, 256 threads, 4x4 per thread.
// EPI 0: QKV scatter (+biases), EPI 1: Rk scatter, EPI 2: direct store.
// ---------------------------------------------------------------------------
template <int EPI>
__global__ __launch_bounds__(256) void gemm_bt(
    const float* __restrict__ A, const float* __restrict__ Bm,
    float* __restrict__ out0, float* __restrict__ out1,
    float* __restrict__ out2, float* __restrict__ out3,
    const float* __restrict__ rwb, const float* __restrict__ rrb,
    int M, int N, int Kd) {
  __shared__ float As[64][17];
  __shared__ float Bs[64][17];
  const int bm = blockIdx.y * 64;
  const int bn = blockIdx.x * 64;
  const int tx = threadIdx.x & 15;
  const int ty = threadIdx.x >> 4;

  float acc[4][4] = {};

  for (int k0 = 0; k0 < Kd; k0 += 16) {
    for (int idx = threadIdx.x; idx < 64 * 16; idx += 256) {
      int r = idx >> 4, c = idx & 15;
      As[r][c] = A[(size_t)(bm + r) * Kd + k0 + c];
      Bs[r][c] = Bm[(size_t)(bn + r) * Kd + k0 + c];
    }
    __syncthreads();
#pragma unroll
    for (int kk = 0; kk < 16; kk++) {
      float a[4], b[4];
#pragma unroll
      for (int i = 0; i < 4; i++) a[i] = As[ty * 4 + i][kk];
#pragma unroll
      for (int j = 0; j < 4; j++) b[j] = Bs[tx * 4 + j][kk];
#pragma unroll
      for (int i = 0; i < 4; i++)
#pragma unroll
        for (int j = 0; j < 4; j++) acc[i][j] += a[i] * b[j];
    }
    __syncthreads();
  }

#pragma unroll
  for (int i = 0; i < 4; i++) {
#pragma unroll
    for (int j = 0; j < 4; j++) {
      int m = bm + ty * 4 + i;
      int n = bn + tx * 4 + j;
      float c = acc[i][j];
      if (EPI == 0) {
        // m = b*T + t ; n in [0, 3*HD)
        int b   = m / Tc, t = m % Tc;
        int sec = n >> 10;         // 0=q, 1=k, 2=v
        int f   = n & 1023;
        int h   = f >> 6, d = f & 63;
        size_t o = (((size_t)(b * Hc + h)) * Tc + t) * 64 + d;
        if (sec == 0) {
          out0[o] = c + rwb[f];    // q + r_w_bias
          out1[o] = c + rrb[f];    // q + r_r_bias
        } else if (sec == 1) {
          out2[o] = c;             // k
        } else {
          out3[o] = c;             // v
        }
      } else if (EPI == 1) {
        // m = r in [0,K), n = h*64+d  ->  Rk[h][r][d]
        int h = n >> 6, d = n & 63;
        out0[((size_t)h * Kc + m) * 64 + d] = c;
      } else {
        out0[(size_t)m * N + n] = c;
      }
    }
  }
}

// ---------------------------------------------------------------------------
// Fused rel-pos attention, flash-style online softmax. fp32.
// Grid: (T/32, H, B). Block: 256 threads = 4 waves; each wave owns 8 q-rows.
// Rel-shift semantics (derived from reference _rel_shift, T==K):
//   j <= i  : BD = (q_i + rr) . Rk[T-1 + j - i]
//   j == i+1: BD = 0
//   j >= i+2: BD = (q_{i+1} + rr) . Rk[j - i - 2]     (wrap rows; NO causal mask)
// Mask: key j invalid iff j >= lens[b]  -> prob 0 (skip fully-masked tiles).
// ---------------------------------------------------------------------------
__global__ __launch_bounds__(256) void attn_kernel(
    const float* __restrict__ qw, const float* __restrict__ qr,
    const float* __restrict__ kk, const float* __restrict__ vv,
    const float* __restrict__ Rk, const int* __restrict__ lens,
    float* __restrict__ vec) {
  constexpr int BI = 32, BJ = 64;
  const int i0   = blockIdx.x * BI;
  const int h    = blockIdx.y;
  const int b    = blockIdx.z;
  const int tid  = threadIdx.x;
  const int w    = tid >> 6;
  const int lane = tid & 63;
  const int len  = lens[b];

  __shared__ float qw_s[BI][65];
  __shared__ float qr_s[BI + 1][65];
  __shared__ float k_s[BJ][65];
  __shared__ float v_s[BJ][65];

  const size_t bh = (size_t)(b * Hc + h) * Tc * 64;
  const float* qwB = qw + bh;
  const float* qrB = qr + bh;
  const float* kB  = kk + bh;
  const float* vB  = vv + bh;
  const float* RkB = Rk + (size_t)h * Kc * 64;

  for (int idx = tid; idx < BI * 64; idx += 256) {
    int r = idx >> 6, c = idx & 63;
    qw_s[r][c] = qwB[(size_t)(i0 + r) * 64 + c];
  }
  for (int idx = tid; idx < (BI + 1) * 64; idx += 256) {
    int r = idx >> 6, c = idx & 63;
    int gi = i0 + r;
    qr_s[r][c] = (gi < Tc) ? qrB[(size_t)gi * 64 + c] : 0.0f;
  }
  __syncthreads();

  float O[8], mrow[8], lrow[8];
#pragma unroll
  for (int r = 0; r < 8; r++) { O[r] = 0.0f; mrow[r] = -1e30f; lrow[r] = 0.0f; }

  for (int j0 = 0; j0 < len; j0 += BJ) {
    __syncthreads();  // protect previous tile's k_s/v_s readers
    for (int idx = tid; idx < BJ * 64; idx += 256) {
      int r = idx >> 6, c = idx & 63;
      k_s[r][c] = kB[(size_t)(j0 + r) * 64 + c];
      v_s[r][c] = vB[(size_t)(j0 + r) * 64 + c];
    }
    __syncthreads();

    const int  jg    = j0 + lane;
    const bool valid = jg < len;

    for (int r = 0; r < 8; r++) {
      const int il = w * 8 + r;
      const int i  = i0 + il;

      // AC = (q_i + rw) . k_j
      float s = 0.0f;
#pragma unroll
      for (int d = 0; d < 64; d++) s += qw_s[il][d] * k_s[lane][d];

      // BD via rel-shift
      float u = 0.0f;
      if (jg <= i) {
        const float* rk = RkB + (size_t)(Tc - 1 + jg - i) * 64;
#pragma unroll
        for (int d = 0; d < 64; d++) u += qr_s[il][d] * rk[d];
      } else if (jg >= i + 2) {
        const float* rk = RkB + (size_t)(jg - i - 2) * 64;
#pragma unroll
        for (int d = 0; d < 64; d++) u += qr_s[il + 1][d] * rk[d];
      }

      s = (s + u) * SCALE;
      s = valid ? s : -1e30f;

      // wave-wide max
      float mx = s;
#pragma unroll
      for (int off = 32; off; off >>= 1) mx = fmaxf(mx, __shfl_xor(mx, off));
      float mnew = fmaxf(mrow[r], mx);

      float p = valid ? __expf(s - mnew) : 0.0f;
      float sum = p;
#pragma unroll
      for (int off = 32; off; off >>= 1) sum += __shfl_xor(sum, off);

      float fac = __expf(mrow[r] - mnew);
      lrow[r] = lrow[r] * fac + sum;

      // PV: lane acts as d. Broadcast p_j via shuffles.
      float accv = O[r] * fac;
#pragma unroll
      for (int j = 0; j < 64; j++) accv += __shfl(p, j) * v_s[j][lane];
      O[r] = accv;
      mrow[r] = mnew;
    }
  }

  // vec[(b*T + i) * HD + h*64 + d]
#pragma unroll
  for (int r = 0; r < 8; r++) {
    int i = i0 + w * 8 + r;
    vec[((size_t)(b * Tc + i)) * HDc + h * 64 + lane] = O[r] / lrow[r];
  }
}

// ---------------------------------------------------------------------------
extern "C" void kernel_launch(void* const* d_in, const int* in_sizes, int n_in,
                              void* d_out, int out_size, void* d_ws, size_t ws_size,
                              hipStream_t stream) {
  const float* we   = (const float*)d_in[0]; // [B,T,E]
  const int*   lens = (const int*)  d_in[1]; // [B]
  const float* Wqkv = (const float*)d_in[2]; // [3*HD, E]
  const float* Wpos = (const float*)d_in[3]; // [HD, E]
  const float* Wout = (const float*)d_in[4]; // [E, HD]
  const float* rwb  = (const float*)d_in[5]; // [H,D]
  const float* rrb  = (const float*)d_in[6]; // [H,D]
  float* out = (float*)d_out;

  // workspace layout (floats): total 46,137,344 floats = 184.5 MB
  float* ws  = (float*)d_ws;
  const size_t BHTD = (size_t)Bc * Hc * Tc * Dc; // 8,388,608
  float* qw  = ws;
  float* qr  = qw + BHTD;
  float* kkp = qr + BHTD;
  float* vvp = kkp + BHTD;
  float* Rk  = vvp + BHTD;                 // H*K*D = 2,097,152
  float* pe  = Rk + (size_t)Hc * Kc * Dc;  // K*E   = 2,097,152
  float* vec = pe + (size_t)Kc * Ec;       // B*T*HD = 8,388,608

  // 1) pe table
  {
    int n = Kc * (Ec / 2);
    pe_kernel<<<(n + 255) / 256, 256, 0, stream>>>(pe);
  }
  // 2) Rk = pe @ Wpos^T  -> [H][K][D]
  gemm_bt<1><<<dim3(HDc / 64, Kc / 64), 256, 0, stream>>>(
      pe, Wpos, Rk, nullptr, nullptr, nullptr, nullptr, nullptr, Kc, HDc, Ec);
  // 3) QKV = we @ Wqkv^T -> qw/qr/k/v in [B,H,T,D]
  gemm_bt<0><<<dim3(3 * HDc / 64, (Bc * Tc) / 64), 256, 0, stream>>>(
      we, Wqkv, qw, qr, kkp, vvp, rwb, rrb, Bc * Tc, 3 * HDc, Ec);
  // 4) fused attention -> vec [B*T, HD]
  attn_kernel<<<dim3(Tc / 32, Hc, Bc), 256, 0, stream>>>(
      qw, qr, kkp, vvp, Rk, lens, vec);
  // 5) out = vec @ Wout^T -> [B,T,E]
  gemm_bt<2><<<dim3(Ec / 64, (Bc * Tc) / 64), 256, 0, stream>>>(
      vec, Wout, out, nullptr, nullptr, nullptr, nullptr, nullptr,
      Bc * Tc, Ec, HDc);
}

// Round 2
// 2201.564 us; speedup vs baseline: 5.1276x; 5.1276x over previous
//
#include <hip/hip_runtime.h>
#include <hip/hip_bf16.h>
#include <math.h>

// Problem constants (B,T,E,H,D) = (4,2048,1024,16,64)
constexpr int Bc  = 4;
constexpr int Tc  = 2048;
constexpr int Ec  = 1024;
constexpr int Hc  = 16;
constexpr int Dc  = 64;
constexpr int HDc = Hc * Dc;   // 1024
constexpr int Kc  = Tc;        // 2048 (mems=None)

typedef __bf16 bf16;
typedef __attribute__((ext_vector_type(8))) __bf16 bf16x8;
typedef __attribute__((ext_vector_type(4))) float f32x4;

// ---------------------------------------------------------------------------
// pe table
// ---------------------------------------------------------------------------
__global__ void pe_kernel(float* __restrict__ pe) {
  int idx = blockIdx.x * blockDim.x + threadIdx.x;
  if (idx >= Kc * (Ec / 2)) return;
  int r = idx / (Ec / 2);
  int i = idx % (Ec / 2);
  float div = __expf((float)i * -0.017988946039015984f); // -2*ln(10000)/1024
  float ang = (float)r * div;
  pe[(size_t)r * Ec + 2 * i]     = sinf(ang);
  pe[(size_t)r * Ec + 2 * i + 1] = cosf(ang);
}

// ---------------------------------------------------------------------------
// fp32 tiled GEMM: C[m,n] = sum_k A[m,k] * B[n,k]   (B given [N,K])
// EPI 0: QKV scatter -> bf16 qw/qr/k (+biases) and TRANSPOSED v (vT[b,h,d,t])
// EPI 1: Rk scatter -> bf16 [H][K][D]
// EPI 2: fp32 direct store (final out)
// ---------------------------------------------------------------------------
template <int EPI>
__global__ __launch_bounds__(256) void gemm_bt(
    const float* __restrict__ A, const float* __restrict__ Bm,
    void* __restrict__ o0, void* __restrict__ o1,
    void* __restrict__ o2, void* __restrict__ o3,
    const float* __restrict__ rwb, const float* __restrict__ rrb,
    int M, int N, int Kd) {
  __shared__ float As[64][17];
  __shared__ float Bs[64][17];
  const int bm = blockIdx.y * 64;
  const int bn = blockIdx.x * 64;
  const int tx = threadIdx.x & 15;
  const int ty = threadIdx.x >> 4;

  float acc[4][4] = {};

  for (int k0 = 0; k0 < Kd; k0 += 16) {
    for (int idx = threadIdx.x; idx < 64 * 16; idx += 256) {
      int r = idx >> 4, c = idx & 15;
      As[r][c] = A[(size_t)(bm + r) * Kd + k0 + c];
      Bs[r][c] = Bm[(size_t)(bn + r) * Kd + k0 + c];
    }
    __syncthreads();
#pragma unroll
    for (int kk = 0; kk < 16; kk++) {
      float a[4], b[4];
#pragma unroll
      for (int i = 0; i < 4; i++) a[i] = As[ty * 4 + i][kk];
#pragma unroll
      for (int j = 0; j < 4; j++) b[j] = Bs[tx * 4 + j][kk];
#pragma unroll
      for (int i = 0; i < 4; i++)
#pragma unroll
        for (int j = 0; j < 4; j++) acc[i][j] += a[i] * b[j];
    }
    __syncthreads();
  }

#pragma unroll
  for (int i = 0; i < 4; i++) {
#pragma unroll
    for (int j = 0; j < 4; j++) {
      int m = bm + ty * 4 + i;
      int n = bn + tx * 4 + j;
      float c = acc[i][j];
      if (EPI == 0) {
        int bb = m / Tc, t = m % Tc;
        int sec = n >> 10;          // 0=q, 1=k, 2=v
        int f   = n & 1023;
        int hh  = f >> 6, d = f & 63;
        if (sec == 0) {
          size_t o = (((size_t)(bb * Hc + hh)) * Tc + t) * 64 + d;
          ((bf16*)o0)[o] = (bf16)(c + rwb[f]);   // q + r_w_bias
          ((bf16*)o1)[o] = (bf16)(c + rrb[f]);   // q + r_r_bias
        } else if (sec == 1) {
          ((bf16*)o2)[(((size_t)(bb * Hc + hh)) * Tc + t) * 64 + d] = (bf16)c;
        } else {
          // vT[b][h][d][t]
          ((bf16*)o3)[(((size_t)(bb * Hc + hh)) * 64 + d) * Tc + t] = (bf16)c;
        }
      } else if (EPI == 1) {
        // m = pe row, n = h*64+d -> Rk[h][m][d]
        ((bf16*)o0)[((size_t)(n >> 6) * Kc + m) * 64 + (n & 63)] = (bf16)c;
      } else {
        ((float*)o0)[(size_t)m * N + n] = c;
      }
    }
  }
}

// ---------------------------------------------------------------------------
// MFMA fused rel-pos attention. Block = 64 q-rows, 4 waves (16 rows/wave).
// No inter-wave LDS sharing -> no __syncthreads.
// Rel-shift (T==K), verified:
//   j <= i  : BD = (q_i + rr) . Rk[T-1 + j - i]
//   j == i+1: BD = 0
//   j >= i+2: BD = (q_{i+1} + rr) . Rk[j - i - 2]
// Window coordinate w = 63 - ii + jj (ii,jj tile-local), p1 = (T-64-c)+w,
// p2 = (-c-65)+w, c = i0 - j0.
// ---------------------------------------------------------------------------
__global__ __launch_bounds__(256) void attn_mfma(
    const bf16* __restrict__ qw, const bf16* __restrict__ qr,
    const bf16* __restrict__ kbuf, const bf16* __restrict__ vT,
    const bf16* __restrict__ Rk, const int* __restrict__ lens,
    float* __restrict__ vec) {
  const int i0    = blockIdx.x * 64;
  const int h     = blockIdx.y;
  const int b     = blockIdx.z;
  const int tid   = threadIdx.x;
  const int wv    = tid >> 6;
  const int lane  = tid & 63;
  const int g     = lane >> 4;
  const int laneL = lane & 15;
  const int len   = lens[b];

  __shared__ float Gs[4][2][16 * 128];   // per-wave G^T windows (fp32), 64KB
  __shared__ bf16  Ps[4][16 * 64];       // per-wave P tiles, 8KB

  const bf16* qwB = qw   + ((size_t)(b * Hc + h)) * Tc * 64;
  const bf16* qrB = qr   + ((size_t)(b * Hc + h)) * Tc * 64;
  const bf16* kB  = kbuf + ((size_t)(b * Hc + h)) * Tc * 64;
  const bf16* vTB = vT   + ((size_t)(b * Hc + h)) * 64 * Tc;
  const bf16* RkB = Rk   + (size_t)h * Kc * 64;

  // loop-invariant Q fragments (A for AC; B for G-GEMMs)
  const int myrow = i0 + wv * 16 + laneL;
  const int myrow2 = (myrow + 1 < Tc) ? myrow + 1 : Tc - 1;
  bf16x8 aw[2], bq1[2], bq2[2];
#pragma unroll
  for (int kk = 0; kk < 2; kk++) {
    aw[kk]  = *(const bf16x8*)(qwB + (size_t)myrow  * 64 + kk * 32 + g * 8);
    bq1[kk] = *(const bf16x8*)(qrB + (size_t)myrow  * 64 + kk * 32 + g * 8);
    bq2[kk] = *(const bf16x8*)(qrB + (size_t)myrow2 * 64 + kk * 32 + g * 8);
  }

  f32x4 O[4];
  float m_[4], l_[4];
#pragma unroll
  for (int nf = 0; nf < 4; nf++) O[nf] = (f32x4){0.f, 0.f, 0.f, 0.f};
#pragma unroll
  for (int r = 0; r < 4; r++) { m_[r] = -1e30f; l_[r] = 0.0f; }

  float* G1p = &Gs[wv][0][0];
  float* G2p = &Gs[wv][1][0];
  bf16*  Pp  = &Ps[wv][0];

  for (int j0 = 0; j0 < len; j0 += 64) {
    const int c = i0 - j0;

    // ---- AC = Qw . K^T  (S[nf]: 16 rows x 16 cols, jj = nf*16+laneL)
    f32x4 S[4];
#pragma unroll
    for (int nf = 0; nf < 4; nf++) {
      f32x4 acc = (f32x4){0.f, 0.f, 0.f, 0.f};
#pragma unroll
      for (int kk = 0; kk < 2; kk++) {
        bf16x8 bk = *(const bf16x8*)(kB + (size_t)(j0 + nf * 16 + laneL) * 64 + kk * 32 + g * 8);
        acc = __builtin_amdgcn_mfma_f32_16x16x32_bf16(aw[kk], bk, acc, 0, 0, 0);
      }
      S[nf] = acc;
    }

    // ---- G1 window (branch j<=i), G^T = mfma(RkW rows, Qr cols)
    if (c >= -63) {
      const int pbase = Tc - 64 - c;
#pragma unroll
      for (int mf = 0; mf < 5; mf++) {
        const int wb = (3 - wv + mf) * 16;
        int p = pbase + wb + laneL;
        p = p < 0 ? 0 : (p > Kc - 1 ? Kc - 1 : p);
        f32x4 acc = (f32x4){0.f, 0.f, 0.f, 0.f};
#pragma unroll
        for (int kk = 0; kk < 2; kk++) {
          bf16x8 ark = *(const bf16x8*)(RkB + (size_t)p * 64 + kk * 32 + g * 8);
          acc = __builtin_amdgcn_mfma_f32_16x16x32_bf16(ark, bq1[kk], acc, 0, 0, 0);
        }
        *(f32x4*)(G1p + laneL * 128 + ((wb + g * 4) ^ ((laneL & 7) << 2))) = acc;
      }
    }
    // ---- G2 window (branch j>=i+2, uses q_{i+1})
    if (c <= 61) {
      const int pbase = -c - 65;
#pragma unroll
      for (int mf = 0; mf < 5; mf++) {
        const int wb = (3 - wv + mf) * 16;
        int p = pbase + wb + laneL;
        p = p < 0 ? 0 : (p > Kc - 1 ? Kc - 1 : p);
        f32x4 acc = (f32x4){0.f, 0.f, 0.f, 0.f};
#pragma unroll
        for (int kk = 0; kk < 2; kk++) {
          bf16x8 ark = *(const bf16x8*)(RkB + (size_t)p * 64 + kk * 32 + g * 8);
          acc = __builtin_amdgcn_mfma_f32_16x16x32_bf16(ark, bq2[kk], acc, 0, 0, 0);
        }
        *(f32x4*)(G2p + laneL * 128 + ((wb + g * 4) ^ ((laneL & 7) << 2))) = acc;
      }
    }

    // ---- score assembly + online softmax (per C-row r)
#pragma unroll
    for (int r = 0; r < 4; r++) {
      const int il  = g * 4 + r;       // row within wave
      const int ii  = wv * 16 + il;    // row within 64-tile
      const int swz = (il & 7) << 2;
      float sc[4];
#pragma unroll
      for (int nf = 0; nf < 4; nf++) {
        const int jj = nf * 16 + laneL;
        const int w  = 63 - ii + jj;
        float g1 = G1p[il * 128 + (w ^ swz)];
        float g2 = G2p[il * 128 + (w ^ swz)];
        float bd = (jj <= ii + c) ? g1 : ((jj == ii + c + 1) ? 0.0f : g2);
        float s  = (S[nf][r] + bd) * 0.125f;
        sc[nf]   = (j0 + jj < len) ? s : -1e30f;
      }
      float mx = fmaxf(fmaxf(sc[0], sc[1]), fmaxf(sc[2], sc[3]));
#pragma unroll
      for (int off = 1; off < 16; off <<= 1) mx = fmaxf(mx, __shfl_xor(mx, off));
      float mnew = fmaxf(m_[r], mx);
      float fac  = __expf(m_[r] - mnew);
      float sum  = 0.0f;
#pragma unroll
      for (int nf = 0; nf < 4; nf++) {
        float p = __expf(sc[nf] - mnew);
        sc[nf] = p;
        sum += p;
      }
#pragma unroll
      for (int off = 1; off < 16; off <<= 1) sum += __shfl_xor(sum, off);
      l_[r] = l_[r] * fac + sum;
      m_[r] = mnew;
#pragma unroll
      for (int nf = 0; nf < 4; nf++) {
        O[nf][r] *= fac;
        Pp[il * 64 + ((nf * 16 + laneL) ^ ((il & 7) << 3))] = (bf16)sc[nf];
      }
    }

    // ---- PV: O += P . V   (A = P from LDS, B = vT rows contiguous)
#pragma unroll
    for (int kk = 0; kk < 2; kk++) {
      bf16x8 pa = *(const bf16x8*)(Pp + laneL * 64 + ((kk * 32 + g * 8) ^ ((laneL & 7) << 3)));
#pragma unroll
      for (int nf = 0; nf < 4; nf++) {
        bf16x8 bv = *(const bf16x8*)(vTB + (size_t)(nf * 16 + laneL) * Tc + j0 + kk * 32 + g * 8);
        O[nf] = __builtin_amdgcn_mfma_f32_16x16x32_bf16(pa, bv, O[nf], 0, 0, 0);
      }
    }
  }

  // ---- writeout: vec[b*T + i][h*64 + d]
#pragma unroll
  for (int r = 0; r < 4; r++) {
    float inv = 1.0f / l_[r];
    int irow  = i0 + wv * 16 + g * 4 + r;
#pragma unroll
    for (int nf = 0; nf < 4; nf++) {
      vec[((size_t)(b * Tc + irow)) * HDc + h * 64 + nf * 16 + laneL] = O[nf][r] * inv;
    }
  }
}

// ---------------------------------------------------------------------------
extern "C" void kernel_launch(void* const* d_in, const int* in_sizes, int n_in,
                              void* d_out, int out_size, void* d_ws, size_t ws_size,
                              hipStream_t stream) {
  const float* we   = (const float*)d_in[0]; // [B,T,E]
  const int*   lens = (const int*)  d_in[1]; // [B]
  const float* Wqkv = (const float*)d_in[2]; // [3*HD, E]
  const float* Wpos = (const float*)d_in[3]; // [HD, E]
  const float* Wout = (const float*)d_in[4]; // [E, HD]
  const float* rwb  = (const float*)d_in[5]; // [H,D]
  const float* rrb  = (const float*)d_in[6]; // [H,D]
  float* out = (float*)d_out;

  // workspace layout
  char* ws = (char*)d_ws;
  const size_t BHTD = (size_t)Bc * Hc * Tc * Dc;           // 8,388,608
  bf16*  qw  = (bf16*)ws;                                   //  16.78 MB
  bf16*  qr  = qw  + BHTD;                                  //  16.78 MB
  bf16*  kkp = qr  + BHTD;                                  //  16.78 MB
  bf16*  vTp = kkp + BHTD;                                  //  16.78 MB (transposed)
  bf16*  Rk  = vTp + BHTD;                                  //   4.19 MB
  float* pe  = (float*)(Rk + (size_t)Hc * Kc * Dc);         //   8.39 MB
  float* vec = pe + (size_t)Kc * Ec;                        //  33.55 MB

  // 1) pe table
  {
    int n = Kc * (Ec / 2);
    pe_kernel<<<(n + 255) / 256, 256, 0, stream>>>(pe);
  }
  // 2) Rk = pe @ Wpos^T -> bf16 [H][K][D]
  gemm_bt<1><<<dim3(HDc / 64, Kc / 64), 256, 0, stream>>>(
      pe, Wpos, Rk, nullptr, nullptr, nullptr, nullptr, nullptr, Kc, HDc, Ec);
  // 3) QKV = we @ Wqkv^T -> bf16 qw/qr/k [B,H,T,D] + vT [B,H,D,T]
  gemm_bt<0><<<dim3(3 * HDc / 64, (Bc * Tc) / 64), 256, 0, stream>>>(
      we, Wqkv, qw, qr, kkp, vTp, rwb, rrb, Bc * Tc, 3 * HDc, Ec);
  // 4) fused MFMA attention -> vec [B*T, HD] fp32
  attn_mfma<<<dim3(Tc / 64, Hc, Bc), 256, 0, stream>>>(
      qw, qr, kkp, vTp, Rk, lens, vec);
  // 5) out = vec @ Wout^T -> [B,T,E] fp32
  gemm_bt<2><<<dim3(Ec / 64, (Bc * Tc) / 64), 256, 0, stream>>>(
      vec, Wout, out, nullptr, nullptr, nullptr, nullptr, nullptr,
      Bc * Tc, Ec, HDc);
}

// Round 3
// 839.290 us; speedup vs baseline: 13.4505x; 2.6231x over previous
//
#include <hip/hip_runtime.h>
#include <hip/hip_bf16.h>
#include <math.h>
#include <stdint.h>

// Problem constants (B,T,E,H,D) = (4,2048,1024,16,64)
constexpr int Bc  = 4;
constexpr int Tc  = 2048;
constexpr int Ec  = 1024;
constexpr int Hc  = 16;
constexpr int Dc  = 64;
constexpr int HDc = Hc * Dc;   // 1024
constexpr int Kc  = Tc;        // 2048 (mems=None)

typedef __bf16 bf16;
typedef __attribute__((ext_vector_type(8))) __bf16 bf16x8;
typedef __attribute__((ext_vector_type(4))) __bf16 bf16x4;
typedef __attribute__((ext_vector_type(4))) float f32x4;

// ---------------------------------------------------------------------------
// async global->LDS, 16B per lane. LDS dest is wave-uniform base + lane*16.
// ---------------------------------------------------------------------------
__device__ __forceinline__ void gload16(const bf16* gp, bf16* lp) {
  __builtin_amdgcn_global_load_lds(
      (const __attribute__((address_space(1))) void*)gp,
      (__attribute__((address_space(3))) void*)lp, 16, 0, 0);
}

// ---------------------------------------------------------------------------
// fp32 -> bf16 hi/lo split (a = hi + lo, |residual| ~ 2^-18 |a|)
// ---------------------------------------------------------------------------
__global__ __launch_bounds__(256) void split_kernel(
    const float* __restrict__ src, bf16* __restrict__ hi,
    bf16* __restrict__ lo, int n) {
  int i = (blockIdx.x * 256 + threadIdx.x) * 4;
  if (i >= n) return;
  float4 v = *(const float4*)(src + i);
  bf16 h0 = (bf16)v.x, h1 = (bf16)v.y, h2 = (bf16)v.z, h3 = (bf16)v.w;
  bf16x4 H = {h0, h1, h2, h3};
  bf16x4 L = {(bf16)(v.x - (float)h0), (bf16)(v.y - (float)h1),
              (bf16)(v.z - (float)h2), (bf16)(v.w - (float)h3)};
  *(bf16x4*)(hi + i) = H;
  *(bf16x4*)(lo + i) = L;
}

// ---------------------------------------------------------------------------
// pe table, emitted directly as hi/lo bf16
// ---------------------------------------------------------------------------
__global__ __launch_bounds__(256) void pe_kernel(bf16* __restrict__ peH,
                                                 bf16* __restrict__ peL) {
  int idx = blockIdx.x * blockDim.x + threadIdx.x;
  if (idx >= Kc * (Ec / 2)) return;
  int r = idx / (Ec / 2);
  int i = idx % (Ec / 2);
  float div = __expf((float)i * -0.017988946039015984f); // -2*ln(10000)/1024
  float ang = (float)r * div;
  float s = sinf(ang), c = cosf(ang);
  bf16 sh = (bf16)s, ch = (bf16)c;
  size_t o = (size_t)r * Ec + 2 * i;
  peH[o]     = sh;
  peH[o + 1] = ch;
  peL[o]     = (bf16)(s - (float)sh);
  peL[o + 1] = (bf16)(c - (float)ch);
}

// ---------------------------------------------------------------------------
// Split-bf16 MFMA GEMM: C[m,n] = sum_k A[m,k]*B[n,k], A=Ah+Al, B=Bh+Bl.
// 3 MFMA passes: Ah*Bh + Ah*Bl + Al*Bh  (Al*Bl dropped, ~2^-18 rel).
// 128x128 tile, BK=64, 256 threads = 4 waves (2x2), 4x4 16x16x32 frags/wave.
// LDS XOR-swizzle (slot ^= row&7) with pre-swizzled global_load_lds source.
// EPI 0: QKV scatter (+biases, vT transpose), EPI 1: Rk scatter, EPI 2: fp32.
// ---------------------------------------------------------------------------
template <int EPI>
__global__ __launch_bounds__(256) void gemm_mfma(
    const bf16* __restrict__ Ah_g, const bf16* __restrict__ Al_g,
    const bf16* __restrict__ Bh_g, const bf16* __restrict__ Bl_g,
    void* __restrict__ o0, void* __restrict__ o1,
    void* __restrict__ o2, void* __restrict__ o3,
    const float* __restrict__ rwb, const float* __restrict__ rrb,
    int Kd) {
  const int bn = blockIdx.x * 128, bm = blockIdx.y * 128;
  const int tid = threadIdx.x, wv = tid >> 6, lane = tid & 63;
  const int wm = wv >> 1, wn = wv & 1;
  const int g = lane >> 4, laneL = lane & 15;

  __shared__ bf16 lds[4 * 128 * 64];
  bf16* Ah = lds;
  bf16* Al = lds + 8192;
  bf16* Bh = lds + 16384;
  bf16* Bl = lds + 24576;

  f32x4 acc[4][4];
#pragma unroll
  for (int fi = 0; fi < 4; fi++)
#pragma unroll
    for (int fj = 0; fj < 4; fj++) acc[fi][fj] = (f32x4){0.f, 0.f, 0.f, 0.f};

  const int rb  = lane >> 3;                 // 0..7 (row within 8-row group)
  const int cb8 = ((lane & 7) ^ rb) * 8;     // pre-swizzled 16B block (elems)
  const bf16* Abase_h = Ah_g + (size_t)bm * Kd;
  const bf16* Abase_l = Al_g + (size_t)bm * Kd;
  const bf16* Bbase_h = Bh_g + (size_t)bn * Kd;
  const bf16* Bbase_l = Bl_g + (size_t)bn * Kd;

  for (int k0 = 0; k0 < Kd; k0 += 64) {
    __syncthreads();
#pragma unroll
    for (int t = 0; t < 4; t++) {
      int r = t * 32 + wv * 8 + rb;
      size_t go = (size_t)r * Kd + k0 + cb8;
      int lo_ = (t * 32 + wv * 8) * 64;
      gload16(Abase_h + go, Ah + lo_);
      gload16(Abase_l + go, Al + lo_);
      gload16(Bbase_h + go, Bh + lo_);
      gload16(Bbase_l + go, Bl + lo_);
    }
    __syncthreads();
#pragma unroll
    for (int kk = 0; kk < 2; kk++) {
      bf16x8 afh[4], afl[4], bfh[4], bfl[4];
#pragma unroll
      for (int fi = 0; fi < 4; fi++) {
        int row = wm * 64 + fi * 16 + laneL;
        int off = row * 64 + (((kk * 4 + g) ^ (row & 7)) * 8);
        afh[fi] = *(const bf16x8*)(Ah + off);
        afl[fi] = *(const bf16x8*)(Al + off);
      }
#pragma unroll
      for (int fj = 0; fj < 4; fj++) {
        int row = wn * 64 + fj * 16 + laneL;
        int off = row * 64 + (((kk * 4 + g) ^ (row & 7)) * 8);
        bfh[fj] = *(const bf16x8*)(Bh + off);
        bfl[fj] = *(const bf16x8*)(Bl + off);
      }
#pragma unroll
      for (int fi = 0; fi < 4; fi++)
#pragma unroll
        for (int fj = 0; fj < 4; fj++) {
          acc[fi][fj] = __builtin_amdgcn_mfma_f32_16x16x32_bf16(afh[fi], bfh[fj], acc[fi][fj], 0, 0, 0);
          acc[fi][fj] = __builtin_amdgcn_mfma_f32_16x16x32_bf16(afh[fi], bfl[fj], acc[fi][fj], 0, 0, 0);
          acc[fi][fj] = __builtin_amdgcn_mfma_f32_16x16x32_bf16(afl[fi], bfh[fj], acc[fi][fj], 0, 0, 0);
        }
    }
  }

  // ---- epilogue. C row = g*4+reg (m-dim), col = laneL (n-dim)
#pragma unroll
  for (int fi = 0; fi < 4; fi++) {
#pragma unroll
    for (int fj = 0; fj < 4; fj++) {
      int n = bn + wn * 64 + fj * 16 + laneL;
      int sec = n >> 10, f = n & 1023, hh = f >> 6, d = f & 63;
      float rw = 0.f, rr = 0.f;
      if (EPI == 0 && sec == 0) { rw = rwb[f]; rr = rrb[f]; }
#pragma unroll
      for (int rg = 0; rg < 4; rg++) {
        int m = bm + wm * 64 + fi * 16 + g * 4 + rg;
        float cv = acc[fi][fj][rg];
        if (EPI == 0) {
          int bb = m >> 11, t = m & 2047;
          if (sec == 0) {
            size_t o = (((size_t)(bb * Hc + hh)) * Tc + t) * 64 + d;
            ((bf16*)o0)[o] = (bf16)(cv + rw);    // q + r_w_bias
            ((bf16*)o1)[o] = (bf16)(cv + rr);    // q + r_r_bias
          } else if (sec == 1) {
            ((bf16*)o2)[(((size_t)(bb * Hc + hh)) * Tc + t) * 64 + d] = (bf16)cv;
          } else {
            ((bf16*)o3)[(((size_t)(bb * Hc + hh)) * 64 + d) * Tc + t] = (bf16)cv; // vT
          }
        } else if (EPI == 1) {
          // m = pe row, n = h*64+d -> Rk[h][m][d]
          ((bf16*)o0)[((size_t)(n >> 6) * Kc + m) * 64 + (n & 63)] = (bf16)cv;
        } else {
          ((float*)o0)[(size_t)m * 1024 + n] = cv;
        }
      }
    }
  }
}

// ---------------------------------------------------------------------------
// MFMA fused rel-pos attention (unchanged except hi/lo vec writeout).
// Rel-shift (T==K):
//   j <= i  : BD = (q_i + rr) . Rk[T-1 + j - i]
//   j == i+1: BD = 0
//   j >= i+2: BD = (q_{i+1} + rr) . Rk[j - i - 2]
// ---------------------------------------------------------------------------
__global__ __launch_bounds__(256) void attn_mfma(
    const bf16* __restrict__ qw, const bf16* __restrict__ qr,
    const bf16* __restrict__ kbuf, const bf16* __restrict__ vT,
    const bf16* __restrict__ Rk, const int* __restrict__ lens,
    bf16* __restrict__ vecH, bf16* __restrict__ vecL) {
  const int i0    = blockIdx.x * 64;
  const int h     = blockIdx.y;
  const int b     = blockIdx.z;
  const int tid   = threadIdx.x;
  const int wv    = tid >> 6;
  const int lane  = tid & 63;
  const int g     = lane >> 4;
  const int laneL = lane & 15;
  const int len   = lens[b];

  __shared__ float Gs[4][2][16 * 128];   // per-wave G^T windows (fp32), 64KB
  __shared__ bf16  Ps[4][16 * 64];       // per-wave P tiles, 8KB

  const bf16* qwB = qw   + ((size_t)(b * Hc + h)) * Tc * 64;
  const bf16* qrB = qr   + ((size_t)(b * Hc + h)) * Tc * 64;
  const bf16* kB  = kbuf + ((size_t)(b * Hc + h)) * Tc * 64;
  const bf16* vTB = vT   + ((size_t)(b * Hc + h)) * 64 * Tc;
  const bf16* RkB = Rk   + (size_t)h * Kc * 64;

  const int myrow = i0 + wv * 16 + laneL;
  const int myrow2 = (myrow + 1 < Tc) ? myrow + 1 : Tc - 1;
  bf16x8 aw[2], bq1[2], bq2[2];
#pragma unroll
  for (int kk = 0; kk < 2; kk++) {
    aw[kk]  = *(const bf16x8*)(qwB + (size_t)myrow  * 64 + kk * 32 + g * 8);
    bq1[kk] = *(const bf16x8*)(qrB + (size_t)myrow  * 64 + kk * 32 + g * 8);
    bq2[kk] = *(const bf16x8*)(qrB + (size_t)myrow2 * 64 + kk * 32 + g * 8);
  }

  f32x4 O[4];
  float m_[4], l_[4];
#pragma unroll
  for (int nf = 0; nf < 4; nf++) O[nf] = (f32x4){0.f, 0.f, 0.f, 0.f};
#pragma unroll
  for (int r = 0; r < 4; r++) { m_[r] = -1e30f; l_[r] = 0.0f; }

  float* G1p = &Gs[wv][0][0];
  float* G2p = &Gs[wv][1][0];
  bf16*  Pp  = &Ps[wv][0];

  for (int j0 = 0; j0 < len; j0 += 64) {
    const int c = i0 - j0;

    f32x4 S[4];
#pragma unroll
    for (int nf = 0; nf < 4; nf++) {
      f32x4 acc = (f32x4){0.f, 0.f, 0.f, 0.f};
#pragma unroll
      for (int kk = 0; kk < 2; kk++) {
        bf16x8 bk = *(const bf16x8*)(kB + (size_t)(j0 + nf * 16 + laneL) * 64 + kk * 32 + g * 8);
        acc = __builtin_amdgcn_mfma_f32_16x16x32_bf16(aw[kk], bk, acc, 0, 0, 0);
      }
      S[nf] = acc;
    }

    if (c >= -63) {
      const int pbase = Tc - 64 - c;
#pragma unroll
      for (int mf = 0; mf < 5; mf++) {
        const int wb = (3 - wv + mf) * 16;
        int p = pbase + wb + laneL;
        p = p < 0 ? 0 : (p > Kc - 1 ? Kc - 1 : p);
        f32x4 acc = (f32x4){0.f, 0.f, 0.f, 0.f};
#pragma unroll
        for (int kk = 0; kk < 2; kk++) {
          bf16x8 ark = *(const bf16x8*)(RkB + (size_t)p * 64 + kk * 32 + g * 8);
          acc = __builtin_amdgcn_mfma_f32_16x16x32_bf16(ark, bq1[kk], acc, 0, 0, 0);
        }
        *(f32x4*)(G1p + laneL * 128 + ((wb + g * 4) ^ ((laneL & 7) << 2))) = acc;
      }
    }
    if (c <= 61) {
      const int pbase = -c - 65;
#pragma unroll
      for (int mf = 0; mf < 5; mf++) {
        const int wb = (3 - wv + mf) * 16;
        int p = pbase + wb + laneL;
        p = p < 0 ? 0 : (p > Kc - 1 ? Kc - 1 : p);
        f32x4 acc = (f32x4){0.f, 0.f, 0.f, 0.f};
#pragma unroll
        for (int kk = 0; kk < 2; kk++) {
          bf16x8 ark = *(const bf16x8*)(RkB + (size_t)p * 64 + kk * 32 + g * 8);
          acc = __builtin_amdgcn_mfma_f32_16x16x32_bf16(ark, bq2[kk], acc, 0, 0, 0);
        }
        *(f32x4*)(G2p + laneL * 128 + ((wb + g * 4) ^ ((laneL & 7) << 2))) = acc;
      }
    }

#pragma unroll
    for (int r = 0; r < 4; r++) {
      const int il  = g * 4 + r;
      const int ii  = wv * 16 + il;
      const int swz = (il & 7) << 2;
      float sc[4];
#pragma unroll
      for (int nf = 0; nf < 4; nf++) {
        const int jj = nf * 16 + laneL;
        const int w  = 63 - ii + jj;
        float g1 = G1p[il * 128 + (w ^ swz)];
        float g2 = G2p[il * 128 + (w ^ swz)];
        float bd = (jj <= ii + c) ? g1 : ((jj == ii + c + 1) ? 0.0f : g2);
        float s  = (S[nf][r] + bd) * 0.125f;
        sc[nf]   = (j0 + jj < len) ? s : -1e30f;
      }
      float mx = fmaxf(fmaxf(sc[0], sc[1]), fmaxf(sc[2], sc[3]));
#pragma unroll
      for (int off = 1; off < 16; off <<= 1) mx = fmaxf(mx, __shfl_xor(mx, off));
      float mnew = fmaxf(m_[r], mx);
      float fac  = __expf(m_[r] - mnew);
      float sum  = 0.0f;
#pragma unroll
      for (int nf = 0; nf < 4; nf++) {
        float p = __expf(sc[nf] - mnew);
        sc[nf] = p;
        sum += p;
      }
#pragma unroll
      for (int off = 1; off < 16; off <<= 1) sum += __shfl_xor(sum, off);
      l_[r] = l_[r] * fac + sum;
      m_[r] = mnew;
#pragma unroll
      for (int nf = 0; nf < 4; nf++) {
        O[nf][r] *= fac;
        Pp[il * 64 + ((nf * 16 + laneL) ^ ((il & 7) << 3))] = (bf16)sc[nf];
      }
    }

#pragma unroll
    for (int kk = 0; kk < 2; kk++) {
      bf16x8 pa = *(const bf16x8*)(Pp + laneL * 64 + ((kk * 32 + g * 8) ^ ((laneL & 7) << 3)));
#pragma unroll
      for (int nf = 0; nf < 4; nf++) {
        bf16x8 bv = *(const bf16x8*)(vTB + (size_t)(nf * 16 + laneL) * Tc + j0 + kk * 32 + g * 8);
        O[nf] = __builtin_amdgcn_mfma_f32_16x16x32_bf16(pa, bv, O[nf], 0, 0, 0);
      }
    }
  }

#pragma unroll
  for (int r = 0; r < 4; r++) {
    float inv = 1.0f / l_[r];
    int irow  = i0 + wv * 16 + g * 4 + r;
#pragma unroll
    for (int nf = 0; nf < 4; nf++) {
      float o = O[nf][r] * inv;
      bf16 hb = (bf16)o;
      size_t idx = ((size_t)(b * Tc + irow)) * HDc + h * 64 + nf * 16 + laneL;
      vecH[idx] = hb;
      vecL[idx] = (bf16)(o - (float)hb);
    }
  }
}

// ---------------------------------------------------------------------------
extern "C" void kernel_launch(void* const* d_in, const int* in_sizes, int n_in,
                              void* d_out, int out_size, void* d_ws, size_t ws_size,
                              hipStream_t stream) {
  const float* we   = (const float*)d_in[0]; // [B,T,E]
  const int*   lens = (const int*)  d_in[1]; // [B]
  const float* Wqkv = (const float*)d_in[2]; // [3*HD, E]
  const float* Wpos = (const float*)d_in[3]; // [HD, E]
  const float* Wout = (const float*)d_in[4]; // [E, HD]
  const float* rwb  = (const float*)d_in[5]; // [H,D]
  const float* rrb  = (const float*)d_in[6]; // [H,D]
  float* out = (float*)d_out;

  // workspace layout (bf16 elems), total ~167.8 MB
  bf16* ws = (bf16*)d_ws;
  const size_t BHTD = (size_t)Bc * Hc * Tc * Dc;   // 8,388,608
  bf16* qw    = ws;                    // BHTD
  bf16* qr    = qw    + BHTD;
  bf16* kkp   = qr    + BHTD;
  bf16* vTp   = kkp   + BHTD;
  bf16* Rk    = vTp   + BHTD;          // H*K*D = 2,097,152
  bf16* peH   = Rk    + (size_t)Hc * Kc * Dc;
  bf16* peL   = peH   + (size_t)Kc * Ec;           // K*E = 2,097,152 each
  bf16* weH   = peL   + (size_t)Kc * Ec;           // 8,388,608 each
  bf16* weL   = weH   + BHTD;
  bf16* qkvH  = weL   + BHTD;                      // 3,145,728 each
  bf16* qkvL  = qkvH  + (size_t)3 * HDc * Ec;
  bf16* WposH = qkvL  + (size_t)3 * HDc * Ec;      // 1,048,576 each
  bf16* WposL = WposH + (size_t)HDc * Ec;
  bf16* WoutH = WposL + (size_t)HDc * Ec;          // 1,048,576 each
  bf16* WoutL = WoutH + (size_t)Ec * HDc;
  bf16* vecH  = WoutL + (size_t)Ec * HDc;          // 8,388,608 each
  bf16* vecL  = vecH  + BHTD;

  // 1) pe table (hi/lo) + input splits
  pe_kernel<<<(Kc * (Ec / 2) + 255) / 256, 256, 0, stream>>>(peH, peL);
  split_kernel<<<(int)(BHTD / 1024), 256, 0, stream>>>(we, weH, weL, (int)BHTD);
  split_kernel<<<3 * HDc * Ec / 1024, 256, 0, stream>>>(Wqkv, qkvH, qkvL, 3 * HDc * Ec);
  split_kernel<<<HDc * Ec / 1024, 256, 0, stream>>>(Wpos, WposH, WposL, HDc * Ec);
  split_kernel<<<Ec * HDc / 1024, 256, 0, stream>>>(Wout, WoutH, WoutL, Ec * HDc);

  // 2) Rk = pe @ Wpos^T -> bf16 [H][K][D]
  gemm_mfma<1><<<dim3(HDc / 128, Kc / 128), 256, 0, stream>>>(
      peH, peL, WposH, WposL, Rk, nullptr, nullptr, nullptr, nullptr, nullptr, Ec);
  // 3) QKV = we @ Wqkv^T -> bf16 qw/qr/k [B,H,T,D] + vT [B,H,D,T]
  gemm_mfma<0><<<dim3(3 * HDc / 128, (Bc * Tc) / 128), 256, 0, stream>>>(
      weH, weL, qkvH, qkvL, qw, qr, kkp, vTp, rwb, rrb, Ec);
  // 4) fused MFMA attention -> vecH/vecL [B*T, HD]
  attn_mfma<<<dim3(Tc / 64, Hc, Bc), 256, 0, stream>>>(
      qw, qr, kkp, vTp, Rk, lens, vecH, vecL);
  // 5) out = vec @ Wout^T -> [B,T,E] fp32
  gemm_mfma<2><<<dim3(Ec / 128, (Bc * Tc) / 128), 256, 0, stream>>>(
      vecH, vecL, WoutH, WoutL, out, nullptr, nullptr, nullptr, nullptr, nullptr, HDc);
}